// Round 4
// baseline (461.498 us; speedup 1.0000x reference)
//
#include <hip/hip_runtime.h>

// Problem: B=16, N=128, F=64, K=128, C=3 (all fp32)
//   pa = S @ w[:F]  (+ b)     -> (B*N, K)
//   pb = S @ w[F:]            -> (B*N, K)
//   out[b,i,j,c,k] = (pa[b,i,k] + pb[b,j,k]) * dist[b,i,j,c]
// out = 402.65 MB fp32 -> HBM-write-bound.
//
// History: 2048-block expands (8192 resident waves) hit ~2.5 TB/s effective
// regardless of read path (L2/LDS), store type (NT/plain), or front shape.
// The harness fill hits 6.28 TB/s at ~10% occupancy (~1000 waves).
// This version clones the fill's launch regime: 256 blocks x 384 threads
// (1536 waves, 6/CU), grid-stride over out with stride = 8 output rows so the
// in-row decode (j, c, kq) is loop-invariant. Inner loop: 3 cached loads +
// 8 VALU + 1 plain dwordx4 store.

#define BN   2048      // B*N rows
#define FF   64        // F
#define KK   128       // K

typedef float f4 __attribute__((ext_vector_type(4)));

// Kernel A: per-row mini-GEMM. One block per row r (b*N+i), 128 threads = one k each.
// pa gets bias folded in. W columns (stride-128) are coalesced across k-threads;
// W (64 KB) is L2-resident after first block. (~5 us, verified.)
__global__ __launch_bounds__(128) void proj_kernel(
    const float* __restrict__ S,   // (BN, F)
    const float* __restrict__ W,   // (2F, K)
    const float* __restrict__ bias,// (K,)
    float* __restrict__ pa,        // (BN, K)  = S@W[:F] + bias
    float* __restrict__ pb)        // (BN, K)  = S@W[F:]
{
    __shared__ float s[FF];
    const int r = blockIdx.x;
    const int k = threadIdx.x;
    if (k < FF) s[k] = S[r * FF + k];
    __syncthreads();

    float acc_a = bias[k];
    float acc_b = 0.0f;
#pragma unroll
    for (int f = 0; f < FF; ++f) {
        const float sv = s[f];                 // LDS broadcast, conflict-free
        acc_a = fmaf(sv, W[f * KK + k], acc_a);
        acc_b = fmaf(sv, W[(f + FF) * KK + k], acc_b);
    }
    pa[r * KK + k] = acc_a;
    pb[r * KK + k] = acc_b;
}

// Kernel B: fill-clone expansion.
// Grid: 256 blocks x 384 threads = 98304 threads = 1536 waves (6/CU).
// out has 25165824 float4; stride G*T = 98304 f4 = exactly 8 rows of 12288 f4.
//   F      = it*98304 + gid,  it = 0..255
//   row    = F / 12288 = row0 + 8*it      (row0 = gid/12288, 0..7)
//   f      = gid % 12288                   LOOP-INVARIANT
//   j = f/96, c = (f%96)>>5, kq = f&31     LOOP-INVARIANT
//   b      = row >> 7                      (1 shift in loop)
// Reads: pa (1 MB), pb (1 MB), dist (3 MB) -- L2/L3-resident.
// Stores: plain dwordx4 (the 6.28 TB/s fill uses plain stores).
__global__ __launch_bounds__(384) void expand_kernel(
    const float* __restrict__ dist,  // (B, N, N, C)
    const float* __restrict__ pa,    // (BN, K) incl. bias
    const float* __restrict__ pb,    // (BN, K)
    float* __restrict__ out)         // (B, N, N, C, K)
{
    const int gid = blockIdx.x * 384 + threadIdx.x;   // 0..98303

    int row = gid / 12288;              // 0..7
    const int f  = gid - row * 12288;   // 0..12287, loop-invariant
    const int j  = f / 96;              // 0..127
    const int r  = f - j * 96;          // 0..95
    const int c  = r >> 5;              // 0..2
    const int kq = r & 31;              // 0..31
    const int pboff = j * 32 + kq;      // pb column offset, loop-invariant

    const f4*    __restrict__ pa_p   = (const f4*)pa + (size_t)row * 32 + kq;        // +256/iter
    const f4*    __restrict__ pb_b   = (const f4*)pb;                                 // + b*4096 + pboff
    const float* __restrict__ dist_p = dist + (size_t)row * 384 + j * 3 + c;          // +3072/iter
    f4*          __restrict__ out_p  = (f4*)out + (size_t)gid;                        // +98304/iter

#pragma unroll 8
    for (int it = 0; it < 256; ++it) {
        const f4    p = pa_p[0];
        const int   b = row >> 7;
        const f4    q = pb_b[b * 4096 + pboff];
        const float d = dist_p[0];

        f4 o;
        o.x = (p.x + q.x) * d;
        o.y = (p.y + q.y) * d;
        o.z = (p.z + q.z) * d;
        o.w = (p.w + q.w) * d;
        out_p[0] = o;                   // plain store, like the 6.28 TB/s fill

        row    += 8;
        pa_p   += 256;
        dist_p += 3072;
        out_p  += 98304;
    }
}

extern "C" void kernel_launch(void* const* d_in, const int* in_sizes, int n_in,
                              void* d_out, int out_size, void* d_ws, size_t ws_size,
                              hipStream_t stream) {
    const float* S    = (const float*)d_in[0];  // (16,128,64)
    const float* dist = (const float*)d_in[1];  // (16,128,128,3)
    const float* W    = (const float*)d_in[2];  // (128,128)
    const float* bias = (const float*)d_in[3];  // (128,)
    float* out = (float*)d_out;

    float* pa = (float*)d_ws;                   // BN*K floats = 1 MB
    float* pb = pa + (size_t)BN * KK;           // 1 MB

    proj_kernel<<<BN, 128, 0, stream>>>(S, W, bias, pa, pb);
    expand_kernel<<<256, 384, 0, stream>>>(dist, pa, pb, out);
}